// Round 6
// baseline (312.650 us; speedup 1.0000x reference)
//
#include <hip/hip_runtime.h>
#include <math.h>

#define NSEG 126
#define PI_F 3.14159265358979323846f
#define C8 0.92387953251128675613f   // cos(pi/8)
#define S8 0.38268343236508977173f   // sin(pi/8)
#define R2C 0.70710678118654752440f  // sqrt(2)/2

__device__ __forceinline__ float2 cadd(float2 a, float2 b){ return make_float2(a.x+b.x, a.y+b.y); }
__device__ __forceinline__ float2 csub(float2 a, float2 b){ return make_float2(a.x-b.x, a.y-b.y); }
__device__ __forceinline__ float2 cmulf(float2 a, float c, float s){
    return make_float2(fmaf(-a.y, s, a.x*c), fmaf(a.x, s, a.y*c));
}
__device__ __forceinline__ float2 mulmi(float2 a){ return make_float2(a.y, -a.x); }  // a * (-i)

// DIF radix-2 16-pt FFT, natural input, output position m holds X[br4(m)].
__device__ __forceinline__ void fft16(float2 a[16]) {
    float2 u, d;
    // stage 1 (span 8), twiddle W16^n on difference
    u=a[0]; d=csub(a[0],a[8]);  a[0]=cadd(u,a[8]);   a[8]=d;
    u=a[1]; d=csub(a[1],a[9]);  a[1]=cadd(u,a[9]);   a[9]=cmulf(d,  C8, -S8);
    u=a[2]; d=csub(a[2],a[10]); a[2]=cadd(u,a[10]);  a[10]=cmulf(d, R2C, -R2C);
    u=a[3]; d=csub(a[3],a[11]); a[3]=cadd(u,a[11]);  a[11]=cmulf(d,  S8, -C8);
    u=a[4]; d=csub(a[4],a[12]); a[4]=cadd(u,a[12]);  a[12]=mulmi(d);
    u=a[5]; d=csub(a[5],a[13]); a[5]=cadd(u,a[13]);  a[13]=cmulf(d, -S8, -C8);
    u=a[6]; d=csub(a[6],a[14]); a[6]=cadd(u,a[14]);  a[14]=cmulf(d, -R2C, -R2C);
    u=a[7]; d=csub(a[7],a[15]); a[7]=cadd(u,a[15]);  a[15]=cmulf(d, -C8, -S8);
    // stage 2 (span 4), twiddles W8^n = {1,(R2,-R2),-i,(-R2,-R2)}
    #pragma unroll
    for (int h = 0; h < 16; h += 8) {
        u=a[h+0]; d=csub(a[h+0],a[h+4]); a[h+0]=cadd(u,a[h+4]); a[h+4]=d;
        u=a[h+1]; d=csub(a[h+1],a[h+5]); a[h+1]=cadd(u,a[h+5]); a[h+5]=cmulf(d, R2C, -R2C);
        u=a[h+2]; d=csub(a[h+2],a[h+6]); a[h+2]=cadd(u,a[h+6]); a[h+6]=mulmi(d);
        u=a[h+3]; d=csub(a[h+3],a[h+7]); a[h+3]=cadd(u,a[h+7]); a[h+7]=cmulf(d, -R2C, -R2C);
    }
    // stage 3 (span 2), twiddles {1, -i}
    #pragma unroll
    for (int q = 0; q < 16; q += 4) {
        u=a[q+0]; d=csub(a[q+0],a[q+2]); a[q+0]=cadd(u,a[q+2]); a[q+2]=d;
        u=a[q+1]; d=csub(a[q+1],a[q+3]); a[q+1]=cadd(u,a[q+3]); a[q+3]=mulmi(d);
    }
    // stage 4 (span 1)
    #pragma unroll
    for (int p = 0; p < 16; p += 2) {
        u=a[p]; a[p]=cadd(u,a[p+1]); a[p+1]=csub(u,a[p+1]);
    }
}

// bit-reverse-4 table (compile-time folds under unrolled loops)
__device__ __constant__ int BR4[16] = {0,8,4,12,2,10,6,14,1,9,5,13,3,11,7,15};

// Shared core: given x[n1-or-n2 layout per comments], lane r in [0,16),
// per-group LDS buf gb (260 float2), produce X[r + 16*br4(m')] in x[m'].
// Entry state: x[k] = input element (n1 = r fixed, n2 = k)  [already transposed]
__device__ __forceinline__ void fft256_core(float2 x[16], float2* gb, int r) {
    fft16(x);                                    // x[m] = S[n1=r][k2=br4(m)]
    #pragma unroll
    for (int m = 1; m < 16; m++) {               // middle twiddle W256^{r*br4(m)}
        float s, c;
        __sincosf(-(PI_F / 128.0f) * (float)(r * BR4[m]), &s, &c);
        x[m] = cmulf(x[m], c, s);
    }
    #pragma unroll
    for (int m = 0; m < 16; m++)                 // transpose: buf[k2=br4(m)][n1=r]
        gb[BR4[m] * 16 + ((r + BR4[m]) & 15)] = x[m];
    float2 z[16];
    #pragma unroll
    for (int n1 = 0; n1 < 16; n1++)
        z[n1] = gb[r * 16 + ((n1 + r) & 15)];    // lane r = k2: all n1
    fft16(z);                                    // z[m'] = X[r + 16*br4(m')]
    #pragma unroll
    for (int m = 0; m < 16; m++) x[m] = z[m];
}

// ---------------------------------------------------------------------------
// prep: keep half-plane (c>128 || (c==128 && r>128)); bucket j = 255-c;
// pack (r, (256-r)&255, seg) — natural indices.
// ---------------------------------------------------------------------------
__global__ void prep_zero(float* acc, int* counts) {
    int i = threadIdx.x;                          // 512 threads
    if (i < NSEG * 3) acc[i] = 0.f;
    if (i < 128) counts[i] = 0;
}

__device__ __forceinline__ bool keep_point(int r, int c) {
    return (c > 128) || (c == 128 && r > 128);
}

__global__ void prep_hist(const int* __restrict__ rr, const int* __restrict__ cc,
                          int n, int* counts) {
    int i = blockIdx.x * 256 + threadIdx.x;
    if (i < n) {
        int c = cc[i], r = rr[i];
        if (keep_point(r, c)) atomicAdd(&counts[255 - c], 1);
    }
}

__global__ void prep_scan(const int* __restrict__ counts, int* starts, int* cursor) {
    int lane = threadIdx.x;                      // 64 threads, 2 counts each
    int2 c = reinterpret_cast<const int2*>(counts)[lane];
    int lsum = c.x + c.y;
    int pre = lsum;
    #pragma unroll
    for (int off = 1; off < 64; off <<= 1) {
        int v = __shfl_up(pre, off);
        if (lane >= off) pre += v;
    }
    int excl = pre - lsum;
    int2 outv = make_int2(excl, excl + c.x);
    reinterpret_cast<int2*>(starts)[lane] = outv;
    reinterpret_cast<int2*>(cursor)[lane] = outv;
    if (lane == 63) starts[128] = excl + c.x + c.y;
}

__global__ void prep_scatter(const int* __restrict__ rr, const int* __restrict__ cc,
                             const int* __restrict__ seg, int n, int* cursor,
                             int* b_pack) {
    int i = blockIdx.x * 256 + threadIdx.x;
    if (i < n) {
        int c = cc[i], r = rr[i];
        if (keep_point(r, c)) {
            int j = 255 - c;
            int pos = atomicAdd(&cursor[j], 1);
            b_pack[pos] = r | (((256 - r) & 255) << 8) | (seg[i] << 16);
        }
    }
}

// ---------------------------------------------------------------------------
// Row-pass: packed z = in + i*tgt; 128 thr = 2 waves; wave = 4 rows (16 lanes
// per row). Four-step FFT via LDS 16x16 transpose. Output G[v][x] natural v.
// ---------------------------------------------------------------------------
__global__ __launch_bounds__(128, 4) void rowfft_kernel(
    const float* __restrict__ inp, const float* __restrict__ tgt,
    float2* __restrict__ G, int pair_base)
{
    __shared__ float2 lds[256 * 9];              // 18432 B; also wave bufs (2*1040)
    int tid    = threadIdx.x;
    int wv     = tid >> 6;
    int lane   = tid & 63;
    int g      = lane >> 4;
    int r      = lane & 15;
    int bid    = blockIdx.x;
    int plocal = bid >> 5;
    int rowgrp = bid & 31;                        // 32 blocks/pair, 8 rows each
    int row    = (rowgrp << 3) + (wv << 2) + g;
    size_t base = (((size_t)(pair_base + plocal)) << 16) + ((size_t)row << 8) + (r << 4);
    const float4* s1 = (const float4*)(inp + base);
    const float4* s2 = (const float4*)(tgt + base);

    float4 A[4], B[4];
    #pragma unroll
    for (int i = 0; i < 4; i++) { A[i] = s1[i]; B[i] = s2[i]; }
    float2 x[16];
    #pragma unroll
    for (int i = 0; i < 4; i++) {
        x[4*i+0] = make_float2(A[i].x, B[i].x);
        x[4*i+1] = make_float2(A[i].y, B[i].y);
        x[4*i+2] = make_float2(A[i].z, B[i].z);
        x[4*i+3] = make_float2(A[i].w, B[i].w);
    }
    // lane holds n1=0..15 at n2=r; transpose so lane holds n2=0..15 at n1=r
    float2* gb = lds + wv * 1040 + g * 260;
    #pragma unroll
    for (int n1 = 0; n1 < 16; n1++)
        gb[n1 * 16 + ((r + n1) & 15)] = x[n1];
    float2 y[16];
    #pragma unroll
    for (int n2 = 0; n2 < 16; n2++)
        y[n2] = gb[r * 16 + ((n2 + r) & 15)];

    fft256_core(y, gb, r);                       // y[m'] = X[r + 16*br4(m')]

    __syncthreads();                             // wave bufs dead -> T-tile phase
    int lrow = (wv << 2) + g;
    #pragma unroll
    for (int m = 0; m < 16; m++)
        lds[(r + 16 * BR4[m]) * 9 + lrow] = y[m];
    __syncthreads();

    float2* dst = G + (((size_t)plocal) << 16) + (rowgrp << 3);
    int xl = tid & 7;
    int q8 = tid >> 3;                            // 0..15
    #pragma unroll
    for (int ii = 0; ii < 16; ii++) {
        int q = q8 + (ii << 4);
        dst[q * 256 + xl] = lds[q * 9 + xl];
    }
}

// ---------------------------------------------------------------------------
// Column-pass + gather. 128 thr = 2 waves; wave = 4 columns = 2 buckets.
// Column loaded directly transposed (coalesced). F kept in the wave's LDS buf.
// ---------------------------------------------------------------------------
__global__ __launch_bounds__(128, 4) void colfft_gather_kernel(
    const float2* __restrict__ G, const int* __restrict__ starts,
    const int* __restrict__ b_pack, float* __restrict__ acc)
{
    __shared__ float2 wbufs[2 * 1040];           // 16640 B
    __shared__ float accl[NSEG * 3];
    int tid    = threadIdx.x;
    int wv     = tid >> 6;
    int lane   = tid & 63;
    int g      = lane >> 4;
    int r      = lane & 15;
    int plocal = blockIdx.x >> 5;
    int b      = blockIdx.x & 31;
    int jbase  = (b << 2) + (wv << 1);           // wave's buckets: jbase, jbase+1

    for (int i = tid; i < NSEG * 3; i += 128) accl[i] = 0.f;
    __syncthreads();

    // group -> column: {j+1, 255-j, j+2, 254-j}
    int c = (g == 0) ? (jbase + 1) : (g == 1) ? (255 - jbase)
          : (g == 2) ? (jbase + 2) : (254 - jbase);
    const float2* col = G + (((size_t)plocal) << 16) + ((size_t)c << 8) + r;

    float2 x[16];
    #pragma unroll
    for (int n2 = 0; n2 < 16; n2++) x[n2] = col[n2 << 4];   // x[n2] = col[r+16*n2]

    float2* gb = wbufs + wv * 1040 + g * 260;
    fft256_core(x, gb, r);                       // x[m'] = X[r + 16*br4(m')]

    #pragma unroll
    for (int m = 0; m < 16; m++)                 // F natural order (reuse gb)
        gb[r + 16 * BR4[m]] = x[m];

    // gather (same-wave LDS: in-order, no barrier)
    float2* wbuf = wbufs + wv * 1040;
    #pragma unroll
    for (int kb = 0; kb < 2; kb++) {
        int j = jbase + kb;
        const float2* F_lo = wbuf + (2 * kb) * 260;
        const float2* F_hi = wbuf + (2 * kb + 1) * 260;
        int s0 = starts[j], s1 = starts[j + 1];
        int e  = s0 + lane;
        int pk = (e < s1) ? b_pack[e] : 0;
        while (e < s1) {
            int e2  = e + 64;
            int pk2 = (e2 < s1) ? b_pack[e2] : 0;
            float2 a = F_hi[pk & 255];            // Fp(r, c)
            float2 m = F_lo[(pk >> 8) & 255];     // Fp(-r, -c)
            int sg = pk >> 16;
            float f1x = a.x + m.x, f1y = a.y - m.y;   // 2*F1
            float dx  = a.x - m.x, dy  = a.y + m.y;   // 2i*F2
            atomicAdd(&accl[sg * 3 + 0], f1x * dy - f1y * dx);
            atomicAdd(&accl[sg * 3 + 1], f1x * f1x + f1y * f1y);
            atomicAdd(&accl[sg * 3 + 2], dx * dx + dy * dy);
            e = e2; pk = pk2;
        }
    }
    __syncthreads();

    for (int i = tid; i < NSEG * 3; i += 128) {
        float v = accl[i];
        if (v != 0.f) atomicAdd(&acc[i], v);
    }
}

// ---------------------------------------------------------------------------
__global__ void final_kernel(const float* __restrict__ acc, const float* __restrict__ w,
                             float* __restrict__ out, float scale) {
    int lane = threadIdx.x;                       // 64 threads
    float val = 0.f;
    for (int s = lane; s < NSEG; s += 64) {
        float cr = acc[s * 3 + 0];
        float p1 = acc[s * 3 + 1];
        float p2 = acc[s * 3 + 2];
        float den = p1 * p2;
        float curve = den > 0.f ? fabsf(cr) * rsqrtf(den) : 0.f;
        val += curve * w[s + 1];
    }
    if (lane == 0) val += w[0];                   // curve[0] = 1
    #pragma unroll
    for (int off = 32; off > 0; off >>= 1) val += __shfl_down(val, off);
    if (lane == 0) out[0] = scale * val;
}

// ---------------------------------------------------------------------------
extern "C" void kernel_launch(void* const* d_in, const int* in_sizes, int n_in,
                              void* d_out, int out_size, void* d_ws, size_t ws_size,
                              hipStream_t stream)
{
    const float* inp = (const float*)d_in[0];
    const float* tgt = (const float*)d_in[1];
    const float* wts = (const float*)d_in[2];
    const int*   rr  = (const int*)d_in[3];
    const int*   cc  = (const int*)d_in[4];
    const int*   sg  = (const int*)d_in[5];
    int npts   = in_sizes[3];
    int npairs = in_sizes[0] >> 16;               // B*C (65536 px/img)

    char* ws = (char*)d_ws;
    float* acc    = (float*)(ws + 0);             // 378 floats
    int*   counts = (int*)(ws + 2048);            // 128 ints
    int*   starts = (int*)(ws + 2560);            // 129 ints
    int*   cursor = (int*)(ws + 3584);            // 128 ints
    int*   b_pack = (int*)(ws + 4096);
    size_t goff = 4096 + (size_t)npts * 4;
    goff = (goff + 255) & ~(size_t)255;
    float2* G = (float2*)(ws + goff);

    size_t per_pair = (size_t)256 * 256 * sizeof(float2);   // 512 KiB
    int maxchunk = (int)((ws_size > goff ? (ws_size - goff) : 0) / per_pair);
    if (maxchunk < 1) maxchunk = 1;
    if (maxchunk > npairs) maxchunk = npairs;

    prep_zero<<<1, 512, 0, stream>>>(acc, counts);
    prep_hist<<<(npts + 255) / 256, 256, 0, stream>>>(rr, cc, npts, counts);
    prep_scan<<<1, 64, 0, stream>>>(counts, starts, cursor);
    prep_scatter<<<(npts + 255) / 256, 256, 0, stream>>>(rr, cc, sg, npts, cursor, b_pack);

    for (int pb = 0; pb < npairs; pb += maxchunk) {
        int cp = npairs - pb < maxchunk ? npairs - pb : maxchunk;
        rowfft_kernel<<<cp * 32, 128, 0, stream>>>(inp, tgt, G, pb);
        colfft_gather_kernel<<<cp * 32, 128, 0, stream>>>(G, starts, b_pack, acc);
    }

    final_kernel<<<1, 64, 0, stream>>>(acc, wts, (float*)d_out, (float)npairs);
}